// Round 2
// baseline (963.900 us; speedup 1.0000x reference)
//
#include <hip/hip_runtime.h>
#include <math.h>

// GridEncoder (instant-NGP hash grid) forward, level-phased two-pass, fp16 table.
// Pre-pass: embeddings f32 -> f16 (x4096 scale keeps values in fp16 normal range).
// Pass 1:  level-major dispatch (4096 blocks/level). Hashed-table gathers use
//          nontemporal loads: no L1 allocation -> no 128B line fill per 4-8B
//          gather (the L2->L1 fill port was the round-1 bottleneck). Table
//          stays L2-resident (2MB + 1.5MB input slice < 4MB per-XCD L2).
//          ws written point-chunk-major [chunk][level][256] half2, nt stores.
// Pass 2:  per block: one contiguous 16KB ws read -> LDS -> out[B][32] f32.

#define NUM_LEVELS 16
#define BLOCK 256
#define B_POINTS (1u << 20)
#define LEVEL_BLOCKS (B_POINTS / BLOCK)  // 4096
#define P1 2654435761u
#define P2 805459861u
#define HASH_MASK 524287u

#define EMB_SCALE 4096.0f
#define EMB_INV_SCALE (1.0f / 4096.0f)

// pass2 tile: 256 points x 16 levels, half2 (uint) in LDS
#define T2_PTS 256
#define T2_LROW 260   // uint words per level row: 256 + 4 pad -> 2-way banks (free)

typedef float    vfloat4 __attribute__((ext_vector_type(4)));
typedef unsigned vuint4  __attribute__((ext_vector_type(4)));
typedef _Float16 vhalf2  __attribute__((ext_vector_type(2)));
typedef _Float16 vhalf4  __attribute__((ext_vector_type(4)));

struct Params {
    float    scale[NUM_LEVELS];
    unsigned offset[NUM_LEVELS];
    unsigned G[NUM_LEVELS];
    unsigned hashedMask;
};

// ---------------- Pre-pass: f32 -> f16 table conversion (x4096) -----------
__global__ __launch_bounds__(BLOCK) void convert_kernel(
    const vfloat4* __restrict__ emb4, vhalf4* __restrict__ tab4, unsigned n4)
{
    const unsigned i = blockIdx.x * BLOCK + threadIdx.x;
    if (i >= n4) return;
    const vfloat4 v = emb4[i];
    vhalf4 h;
    h.x = (_Float16)(v.x * EMB_SCALE);
    h.y = (_Float16)(v.y * EMB_SCALE);
    h.z = (_Float16)(v.z * EMB_SCALE);
    h.w = (_Float16)(v.w * EMB_SCALE);
    tab4[i] = h;
}

// ---------------- Pass 1 ----------------
__global__ __launch_bounds__(BLOCK) void grid_level_kernel(
    const float* __restrict__ inp, const _Float16* __restrict__ tab,
    unsigned* __restrict__ ws, Params p)
{
    const unsigned blk   = blockIdx.x;
    const unsigned l     = blk >> 12;                    // level-major dispatch
    const unsigned chunk = blk & 4095u;
    const unsigned b     = (chunk << 8) | threadIdx.x;

    const float    s      = p.scale[l];
    const unsigned G      = p.G[l];
    const unsigned base   = p.offset[l];
    const bool     hashed = (p.hashedMask >> l) & 1u;    // wave-uniform

    const float i0 = inp[3u * b + 0];
    const float i1 = inp[3u * b + 1];
    const float i2 = inp[3u * b + 2];
    const float x0 = __fmul_rn(__fadd_rn(i0, 1.0f), 0.5f);
    const float x1 = __fmul_rn(__fadd_rn(i1, 1.0f), 0.5f);
    const float x2 = __fmul_rn(__fadd_rn(i2, 1.0f), 0.5f);

    const float p0 = __fadd_rn(__fmul_rn(x0, s), 0.5f);
    const float p1 = __fadd_rn(__fmul_rn(x1, s), 0.5f);
    const float p2 = __fadd_rn(__fmul_rn(x2, s), 0.5f);
    const float g0 = floorf(p0), g1 = floorf(p1), g2 = floorf(p2);
    const float f0 = __fsub_rn(p0, g0);
    const float f1 = __fsub_rn(p1, g1);
    const float f2 = __fsub_rn(p2, g2);
    const unsigned u0 = (unsigned)g0, u1 = (unsigned)g1, u2 = (unsigned)g2;
    const float m0 = __fsub_rn(1.0f, f0);
    const float m1 = __fsub_rn(1.0f, f1);
    const float m2 = __fsub_rn(1.0f, f2);

    float a0 = 0.0f, a1 = 0.0f;

    if (hashed) {
        const unsigned h1a = u1 * P1,        h2a = u2 * P2;
        const unsigned h1b = (u1 + 1u) * P1, h2b = (u2 + 1u) * P2;
        if ((u0 & 1u) == 0u) {
            // even u0: corners (u0, u0+1) -> rows {idx, idx^1}: one aligned 8B load
#pragma unroll
            for (int k = 0; k < 4; ++k) {
                const unsigned b1 = (k >> 1) & 1, b2 = k & 1;
                const unsigned h  = (b1 ? h1b : h1a) ^ (b2 ? h2b : h2a);
                const unsigned idx0 = (u0 ^ h) & HASH_MASK;
                const unsigned base2 = idx0 & ~1u;
                const vhalf4 e4 = __builtin_nontemporal_load(
                    reinterpret_cast<const vhalf4*>(tab + 2u * (base + base2)));
                const bool q = (idx0 & 1u);
                const float eax = (float)(q ? e4.z : e4.x);
                const float eay = (float)(q ? e4.w : e4.y);
                const float ebx = (float)(q ? e4.x : e4.z);
                const float eby = (float)(q ? e4.y : e4.w);
                const float w12 = __fmul_rn(b1 ? f1 : m1, b2 ? f2 : m2);
                const float wa = __fmul_rn(m0, w12);
                const float wb = __fmul_rn(f0, w12);
                a0 = fmaf(wa, eax, a0); a1 = fmaf(wa, eay, a1);
                a0 = fmaf(wb, ebx, a0); a1 = fmaf(wb, eby, a1);
            }
        } else {
#pragma unroll
            for (int k = 0; k < 8; ++k) {
                const unsigned bit0 = (k >> 2) & 1, bit1 = (k >> 1) & 1, bit2 = k & 1;
                const unsigned c0 = u0 + bit0;
                const unsigned h  = (bit1 ? h1b : h1a) ^ (bit2 ? h2b : h2a);
                const unsigned idx = (c0 ^ h) & HASH_MASK;
                const unsigned eu = __builtin_nontemporal_load(
                    reinterpret_cast<const unsigned*>(tab + 2u * (base + idx)));
                const vhalf2 e = __builtin_bit_cast(vhalf2, eu);
                const float w = __fmul_rn(__fmul_rn(bit0 ? f0 : m0, bit1 ? f1 : m1),
                                          bit2 ? f2 : m2);
                a0 = fmaf(w, (float)e.x, a0); a1 = fmaf(w, (float)e.y, a1);
            }
        }
    } else {
        // dense: dim0 stride 1 -> rows (r, r+1) always adjacent (8B, maybe 4B-aligned)
        // small low-level tables actually hit L1 -> keep temporal loads here
        const unsigned GG = G * G;
#pragma unroll
        for (int k = 0; k < 4; ++k) {
            const unsigned b1 = (k >> 1) & 1, b2 = k & 1;
            const unsigned r = u0 + (u1 + b1) * G + (u2 + b2) * GG;
            vhalf4 e4;
            __builtin_memcpy(&e4, tab + 2u * (base + r), 8);
            const float w12 = __fmul_rn(b1 ? f1 : m1, b2 ? f2 : m2);
            const float wa = __fmul_rn(m0, w12);
            const float wb = __fmul_rn(f0, w12);
            a0 = fmaf(wa, (float)e4.x, a0); a1 = fmaf(wa, (float)e4.y, a1);
            a0 = fmaf(wb, (float)e4.z, a0); a1 = fmaf(wb, (float)e4.w, a1);
        }
    }

    // streaming result (still x4096-scaled; fp16-safe range)
    // ws layout: [chunk][level][256] half2 -> pass2 reads 16KB contiguous/block
    vhalf2 hv;
    hv.x = (_Float16)a0;
    hv.y = (_Float16)a1;
    __builtin_nontemporal_store(
        __builtin_bit_cast(unsigned, hv),
        ws + (size_t)chunk * (NUM_LEVELS * BLOCK) + l * BLOCK + threadIdx.x);
}

// ---------------- Pass 2: ws[chunk][16][256] -> out[B][32] ------------------
__global__ __launch_bounds__(BLOCK) void transpose_kernel(
    const unsigned* __restrict__ ws, float* __restrict__ out)
{
    __shared__ unsigned tile[NUM_LEVELS * T2_LROW];   // 16 x 260 x 4B = 16.6 KB
    const unsigned t = threadIdx.x;
    const unsigned c = blockIdx.x;

    // load: one contiguous 16KB segment = 1024 uint4; 4 rounds x 256 threads
    const vuint4* src = reinterpret_cast<const vuint4*>(
        ws + (size_t)c * (NUM_LEVELS * T2_PTS));
#pragma unroll
    for (int r = 0; r < 4; ++r) {
        const unsigned flat = r * BLOCK + t;     // uint4 id; 64 uint4 per level
        const unsigned l = flat >> 6;
        const unsigned i = flat & 63u;
        const vuint4 v = __builtin_nontemporal_load(src + flat);
        *reinterpret_cast<vuint4*>(&tile[l * T2_LROW + 4u * i]) = v;
    }
    __syncthreads();

    // store: 256 pts x 8 float4 = 2048; 8 rounds, contiguous 4KB each
    vfloat4* ov = reinterpret_cast<vfloat4*>(out) + (size_t)c * (T2_PTS * 8u);
#pragma unroll
    for (int r = 0; r < 8; ++r) {
        const unsigned idx = r * BLOCK + t;
        const unsigned pt = idx >> 3;
        const unsigned j  = idx & 7u;            // level pair
        const vhalf2 e0 = __builtin_bit_cast(vhalf2, tile[(2u * j)      * T2_LROW + pt]);
        const vhalf2 e1 = __builtin_bit_cast(vhalf2, tile[(2u * j + 1u) * T2_LROW + pt]);
        vfloat4 v;
        v.x = (float)e0.x * EMB_INV_SCALE;
        v.y = (float)e0.y * EMB_INV_SCALE;
        v.z = (float)e1.x * EMB_INV_SCALE;
        v.w = (float)e1.y * EMB_INV_SCALE;
        __builtin_nontemporal_store(v, ov + idx);
    }
}

// ---------------- Fallback: monolithic f32 (used only if ws too small) -----
__global__ __launch_bounds__(BLOCK) void grid_encode_kernel(
    const float* __restrict__ inp, const float2* __restrict__ emb,
    float* __restrict__ out, Params p)
{
    const unsigned b = blockIdx.x * BLOCK + threadIdx.x;
    const float i0 = inp[3u * b + 0], i1 = inp[3u * b + 1], i2 = inp[3u * b + 2];
    const float x0 = __fmul_rn(__fadd_rn(i0, 1.0f), 0.5f);
    const float x1 = __fmul_rn(__fadd_rn(i1, 1.0f), 0.5f);
    const float x2 = __fmul_rn(__fadd_rn(i2, 1.0f), 0.5f);
    float o[2 * NUM_LEVELS];
#pragma unroll
    for (int l = 0; l < NUM_LEVELS; ++l) {
        const float s = p.scale[l];
        const unsigned G = p.G[l], base = p.offset[l];
        const bool hashed = (p.hashedMask >> l) & 1u;
        const float p0 = __fadd_rn(__fmul_rn(x0, s), 0.5f);
        const float p1 = __fadd_rn(__fmul_rn(x1, s), 0.5f);
        const float p2 = __fadd_rn(__fmul_rn(x2, s), 0.5f);
        const float g0 = floorf(p0), g1 = floorf(p1), g2 = floorf(p2);
        const float f0 = __fsub_rn(p0, g0), f1 = __fsub_rn(p1, g1), f2 = __fsub_rn(p2, g2);
        const unsigned u0 = (unsigned)g0, u1 = (unsigned)g1, u2 = (unsigned)g2;
        const float m0 = __fsub_rn(1.0f, f0), m1 = __fsub_rn(1.0f, f1), m2 = __fsub_rn(1.0f, f2);
        float a0 = 0.0f, a1 = 0.0f;
#pragma unroll
        for (int k = 0; k < 8; ++k) {
            const unsigned bit0 = (k >> 2) & 1, bit1 = (k >> 1) & 1, bit2 = k & 1;
            const unsigned c0 = u0 + bit0, c1 = u1 + bit1, c2 = u2 + bit2;
            unsigned idx;
            if (hashed) idx = (c0 ^ (c1 * P1) ^ (c2 * P2)) & HASH_MASK;
            else        idx = c0 + c1 * G + c2 * G * G;
            const float2 e = emb[(size_t)(base + idx)];
            const float w = __fmul_rn(__fmul_rn(bit0 ? f0 : m0, bit1 ? f1 : m1),
                                      bit2 ? f2 : m2);
            a0 = fmaf(w, e.x, a0); a1 = fmaf(w, e.y, a1);
        }
        o[2 * l] = a0; o[2 * l + 1] = a1;
    }
    float4* ov = reinterpret_cast<float4*>(out + (size_t)b * 32u);
#pragma unroll
    for (int j = 0; j < 8; ++j)
        ov[j] = make_float4(o[4 * j], o[4 * j + 1], o[4 * j + 2], o[4 * j + 3]);
}

extern "C" void kernel_launch(void* const* d_in, const int* in_sizes, int n_in,
                              void* d_out, int out_size, void* d_ws, size_t ws_size,
                              hipStream_t stream) {
    const float*  inp = (const float*)d_in[0];
    const float2* emb = (const float2*)d_in[1];
    float*        out = (float*)d_out;

    // Host-side replication of reference level setup (same libm chain as numpy).
    Params p;
    const double PLS = exp2(log2(2048.0 / 16.0) / 15.0);
    const double S   = log2(PLS);
    unsigned off = 0, hashedMask = 0;
    for (int l = 0; l < NUM_LEVELS; ++l) {
        const double sc_d = exp2((double)l * S) * 16.0 - 1.0;
        const float  sc   = (float)sc_d;
        p.scale[l] = sc;
        const unsigned G = (unsigned)ceilf(sc) + 2u;
        p.G[l] = G;
        const unsigned res = (unsigned)(ceil(16.0 * pow(PLS, (double)l))) + 1u;
        unsigned long long cube = (unsigned long long)res * res * res;
        unsigned long long nll  = cube < 524288ull ? cube : 524288ull;
        unsigned n = (unsigned)((nll + 7ull) / 8ull * 8ull);
        p.offset[l] = off;
        if ((unsigned long long)G * G * G > (unsigned long long)n) hashedMask |= (1u << l);
        off += n;
    }
    p.hashedMask = hashedMask;

    // workspace layout: [f16 table (x4096)] [ws half2, chunk-major 16 x B]
    const size_t tabBytes = ((size_t)off * 4u + 4095u) & ~(size_t)4095u;  // ~24 MB
    const size_t wsBytes  = (size_t)NUM_LEVELS * B_POINTS * 4u;           // 64 MB
    const size_t ws_needed = tabBytes + wsBytes;                          // ~88 MB

    if (ws_size >= ws_needed) {
        _Float16* tab  = (_Float16*)d_ws;
        unsigned* ws_u = (unsigned*)((char*)d_ws + tabBytes);
        const unsigned n4 = off / 2u;  // off is a multiple of 8
        convert_kernel<<<(n4 + BLOCK - 1) / BLOCK, BLOCK, 0, stream>>>(
            (const vfloat4*)emb, (vhalf4*)tab, n4);
        grid_level_kernel<<<NUM_LEVELS * LEVEL_BLOCKS, BLOCK, 0, stream>>>(
            inp, tab, ws_u, p);
        transpose_kernel<<<B_POINTS / T2_PTS, BLOCK, 0, stream>>>(ws_u, out);
    } else {
        grid_encode_kernel<<<LEVEL_BLOCKS, BLOCK, 0, stream>>>(inp, emb, out, p);
    }
}

// Round 4
// 751.964 us; speedup vs baseline: 1.2818x; 1.2818x over previous
//
#include <hip/hip_runtime.h>
#include <math.h>

// GridEncoder (instant-NGP hash grid) forward, fused single-pass, fp16 table.
// Pre-pass: embeddings f32 -> f16 (x4096 scale keeps values in fp16 normal range);
//           a hashed level's table is 2MB -> L2-resident per XCD.
// Fused:    each block owns 512 points and loops over all 16 levels in order.
//           All blocks traverse levels in lockstep-ish order, so at any moment
//           only ~1-2 level tables (2-4MB) are hot per L2 (loose phasing keeps
//           the round-1 L2 residency without a ws round-trip). Per-level half2
//           results stage in a 32.8KB LDS tile; after the level loop the block
//           writes out[512][32] f32 fully coalesced (float4). This removes the
//           64MB ws write + 64MB ws read + one dispatch that made up the
//           constant ~175us tail in rounds 0-2.
// NOTE (rounds 2/3): nontemporal loads and sc0-asm gathers on the table are
//           both BANNED - nt evicts L2 (FETCH 159MB->1.36GB), sc0 asm returned
//           wrong data. Table gathers are plain loads (round-1 proven).

#define NUM_LEVELS 16
#define BLOCK 256            // convert / fallback block
#define FBLOCK 512           // fused kernel threads = points per block
#define B_POINTS (1u << 20)
#define P1 2654435761u
#define P2 805459861u
#define HASH_MASK 524287u

#define EMB_SCALE 4096.0f
#define EMB_INV_SCALE (1.0f / 4096.0f)

#define LROW 513             // uint words per LDS level row: 512 + 1 pad

typedef float    vfloat4 __attribute__((ext_vector_type(4)));
typedef _Float16 vhalf2  __attribute__((ext_vector_type(2)));
typedef _Float16 vhalf4  __attribute__((ext_vector_type(4)));

struct Params {
    float    scale[NUM_LEVELS];
    unsigned offset[NUM_LEVELS];
    unsigned G[NUM_LEVELS];
    unsigned hashedMask;
};

// ---------------- Pre-pass: f32 -> f16 table conversion (x4096) -----------
__global__ __launch_bounds__(BLOCK) void convert_kernel(
    const vfloat4* __restrict__ emb4, vhalf4* __restrict__ tab4, unsigned n4)
{
    const unsigned i = blockIdx.x * BLOCK + threadIdx.x;
    if (i >= n4) return;
    const vfloat4 v = emb4[i];
    vhalf4 h;
    h.x = (_Float16)(v.x * EMB_SCALE);
    h.y = (_Float16)(v.y * EMB_SCALE);
    h.z = (_Float16)(v.z * EMB_SCALE);
    h.w = (_Float16)(v.w * EMB_SCALE);
    tab4[i] = h;
}

// ---------------- Fused: 512 points/block, 16-level loop, direct out -------
__global__ __launch_bounds__(FBLOCK) void grid_fused_kernel(
    const float* __restrict__ inp, const _Float16* __restrict__ tab,
    float* __restrict__ out, Params p)
{
    __shared__ unsigned tile[NUM_LEVELS * LROW];   // 16 x 513 x 4B = 32.8 KB

    const unsigned t  = threadIdx.x;
    const unsigned pb = blockIdx.x * FBLOCK;       // first point of block
    const unsigned b  = pb + t;

    const float i0 = inp[3u * b + 0];
    const float i1 = inp[3u * b + 1];
    const float i2 = inp[3u * b + 2];
    const float x0 = __fmul_rn(__fadd_rn(i0, 1.0f), 0.5f);
    const float x1 = __fmul_rn(__fadd_rn(i1, 1.0f), 0.5f);
    const float x2 = __fmul_rn(__fadd_rn(i2, 1.0f), 0.5f);

#pragma unroll 1
    for (int l = 0; l < NUM_LEVELS; ++l) {
        const float    s      = p.scale[l];
        const unsigned G      = p.G[l];
        const unsigned base   = p.offset[l];
        const bool     hashed = (p.hashedMask >> l) & 1u;   // wave-uniform

        const float p0 = __fadd_rn(__fmul_rn(x0, s), 0.5f);
        const float p1 = __fadd_rn(__fmul_rn(x1, s), 0.5f);
        const float p2 = __fadd_rn(__fmul_rn(x2, s), 0.5f);
        const float g0 = floorf(p0), g1 = floorf(p1), g2 = floorf(p2);
        const float f0 = __fsub_rn(p0, g0);
        const float f1 = __fsub_rn(p1, g1);
        const float f2 = __fsub_rn(p2, g2);
        const unsigned u0 = (unsigned)g0, u1 = (unsigned)g1, u2 = (unsigned)g2;
        const float m0 = __fsub_rn(1.0f, f0);
        const float m1 = __fsub_rn(1.0f, f1);
        const float m2 = __fsub_rn(1.0f, f2);

        float a0 = 0.0f, a1 = 0.0f;

        if (hashed) {
            const unsigned h1a = u1 * P1,        h2a = u2 * P2;
            const unsigned h1b = (u1 + 1u) * P1, h2b = (u2 + 1u) * P2;
            if ((u0 & 1u) == 0u) {
                // even u0: corners (u0,u0+1) -> rows {idx, idx^1}: one 8B load
#pragma unroll
                for (int k = 0; k < 4; ++k) {
                    const unsigned b1 = (k >> 1) & 1, b2 = k & 1;
                    const unsigned h  = (b1 ? h1b : h1a) ^ (b2 ? h2b : h2a);
                    const unsigned idx0 = (u0 ^ h) & HASH_MASK;
                    const unsigned base2 = idx0 & ~1u;
                    const vhalf4 e4 = *reinterpret_cast<const vhalf4*>(
                        tab + 2u * (base + base2));
                    const bool q = (idx0 & 1u);
                    const float eax = (float)(q ? e4.z : e4.x);
                    const float eay = (float)(q ? e4.w : e4.y);
                    const float ebx = (float)(q ? e4.x : e4.z);
                    const float eby = (float)(q ? e4.y : e4.w);
                    const float w12 = __fmul_rn(b1 ? f1 : m1, b2 ? f2 : m2);
                    const float wa = __fmul_rn(m0, w12);
                    const float wb = __fmul_rn(f0, w12);
                    a0 = fmaf(wa, eax, a0); a1 = fmaf(wa, eay, a1);
                    a0 = fmaf(wb, ebx, a0); a1 = fmaf(wb, eby, a1);
                }
            } else {
#pragma unroll
                for (int k = 0; k < 8; ++k) {
                    const unsigned bit0 = (k >> 2) & 1, bit1 = (k >> 1) & 1,
                                   bit2 = k & 1;
                    const unsigned c0 = u0 + bit0;
                    const unsigned h  = (bit1 ? h1b : h1a) ^ (bit2 ? h2b : h2a);
                    const unsigned idx = (c0 ^ h) & HASH_MASK;
                    const vhalf2 e = *reinterpret_cast<const vhalf2*>(
                        tab + 2u * (base + idx));
                    const float w = __fmul_rn(
                        __fmul_rn(bit0 ? f0 : m0, bit1 ? f1 : m1),
                        bit2 ? f2 : m2);
                    a0 = fmaf(w, (float)e.x, a0); a1 = fmaf(w, (float)e.y, a1);
                }
            }
        } else {
            // dense: dim0 stride 1 -> rows (r, r+1) adjacent (8B, maybe 4B-aligned)
            const unsigned GG = G * G;
#pragma unroll
            for (int k = 0; k < 4; ++k) {
                const unsigned b1 = (k >> 1) & 1, b2 = k & 1;
                const unsigned r = u0 + (u1 + b1) * G + (u2 + b2) * GG;
                vhalf4 e4;
                __builtin_memcpy(&e4, tab + 2u * (base + r), 8);
                const float w12 = __fmul_rn(b1 ? f1 : m1, b2 ? f2 : m2);
                const float wa = __fmul_rn(m0, w12);
                const float wb = __fmul_rn(f0, w12);
                a0 = fmaf(wa, (float)e4.x, a0); a1 = fmaf(wa, (float)e4.y, a1);
                a0 = fmaf(wb, (float)e4.z, a0); a1 = fmaf(wb, (float)e4.w, a1);
            }
        }

        vhalf2 hv;
        hv.x = (_Float16)a0;
        hv.y = (_Float16)a1;
        tile[(unsigned)l * LROW + t] = __builtin_bit_cast(unsigned, hv);
    }

    __syncthreads();

    // out write: 512 pts x 8 float4 = 4096; 8 rounds x 512 threads, coalesced.
    vfloat4* ov = reinterpret_cast<vfloat4*>(out) + (size_t)pb * 8u;
#pragma unroll
    for (int r = 0; r < 8; ++r) {
        const unsigned idx = r * FBLOCK + t;
        const unsigned pt = idx >> 3;
        const unsigned j  = idx & 7u;            // level pair
        const vhalf2 e0 = __builtin_bit_cast(vhalf2, tile[(2u * j)      * LROW + pt]);
        const vhalf2 e1 = __builtin_bit_cast(vhalf2, tile[(2u * j + 1u) * LROW + pt]);
        vfloat4 v;
        v.x = (float)e0.x * EMB_INV_SCALE;
        v.y = (float)e0.y * EMB_INV_SCALE;
        v.z = (float)e1.x * EMB_INV_SCALE;
        v.w = (float)e1.y * EMB_INV_SCALE;
        __builtin_nontemporal_store(v, ov + idx);  // pure stream, never re-read
    }
}

// ---------------- Fallback: monolithic f32 (used only if ws too small) -----
__global__ __launch_bounds__(BLOCK) void grid_encode_kernel(
    const float* __restrict__ inp, const float2* __restrict__ emb,
    float* __restrict__ out, Params p)
{
    const unsigned b = blockIdx.x * BLOCK + threadIdx.x;
    const float i0 = inp[3u * b + 0], i1 = inp[3u * b + 1], i2 = inp[3u * b + 2];
    const float x0 = __fmul_rn(__fadd_rn(i0, 1.0f), 0.5f);
    const float x1 = __fmul_rn(__fadd_rn(i1, 1.0f), 0.5f);
    const float x2 = __fmul_rn(__fadd_rn(i2, 1.0f), 0.5f);
    float o[2 * NUM_LEVELS];
#pragma unroll
    for (int l = 0; l < NUM_LEVELS; ++l) {
        const float s = p.scale[l];
        const unsigned G = p.G[l], base = p.offset[l];
        const bool hashed = (p.hashedMask >> l) & 1u;
        const float p0 = __fadd_rn(__fmul_rn(x0, s), 0.5f);
        const float p1 = __fadd_rn(__fmul_rn(x1, s), 0.5f);
        const float p2 = __fadd_rn(__fmul_rn(x2, s), 0.5f);
        const float g0 = floorf(p0), g1 = floorf(p1), g2 = floorf(p2);
        const float f0 = __fsub_rn(p0, g0), f1 = __fsub_rn(p1, g1), f2 = __fsub_rn(p2, g2);
        const unsigned u0 = (unsigned)g0, u1 = (unsigned)g1, u2 = (unsigned)g2;
        const float m0 = __fsub_rn(1.0f, f0), m1 = __fsub_rn(1.0f, f1), m2 = __fsub_rn(1.0f, f2);
        float a0 = 0.0f, a1 = 0.0f;
#pragma unroll
        for (int k = 0; k < 8; ++k) {
            const unsigned bit0 = (k >> 2) & 1, bit1 = (k >> 1) & 1, bit2 = k & 1;
            const unsigned c0 = u0 + bit0, c1 = u1 + bit1, c2 = u2 + bit2;
            unsigned idx;
            if (hashed) idx = (c0 ^ (c1 * P1) ^ (c2 * P2)) & HASH_MASK;
            else        idx = c0 + c1 * G + c2 * G * G;
            const float2 e = emb[(size_t)(base + idx)];
            const float w = __fmul_rn(__fmul_rn(bit0 ? f0 : m0, bit1 ? f1 : m1),
                                      bit2 ? f2 : m2);
            a0 = fmaf(w, e.x, a0); a1 = fmaf(w, e.y, a1);
        }
        o[2 * l] = a0; o[2 * l + 1] = a1;
    }
    float4* ov = reinterpret_cast<float4*>(out + (size_t)b * 32u);
#pragma unroll
    for (int j = 0; j < 8; ++j)
        ov[j] = make_float4(o[4 * j], o[4 * j + 1], o[4 * j + 2], o[4 * j + 3]);
}

extern "C" void kernel_launch(void* const* d_in, const int* in_sizes, int n_in,
                              void* d_out, int out_size, void* d_ws, size_t ws_size,
                              hipStream_t stream) {
    const float*  inp = (const float*)d_in[0];
    const float2* emb = (const float2*)d_in[1];
    float*        out = (float*)d_out;

    // Host-side replication of reference level setup (same libm chain as numpy).
    Params p;
    const double PLS = exp2(log2(2048.0 / 16.0) / 15.0);
    const double S   = log2(PLS);
    unsigned off = 0, hashedMask = 0;
    for (int l = 0; l < NUM_LEVELS; ++l) {
        const double sc_d = exp2((double)l * S) * 16.0 - 1.0;
        const float  sc   = (float)sc_d;
        p.scale[l] = sc;
        const unsigned G = (unsigned)ceilf(sc) + 2u;
        p.G[l] = G;
        const unsigned res = (unsigned)(ceil(16.0 * pow(PLS, (double)l))) + 1u;
        unsigned long long cube = (unsigned long long)res * res * res;
        unsigned long long nll  = cube < 524288ull ? cube : 524288ull;
        unsigned n = (unsigned)((nll + 7ull) / 8ull * 8ull);
        p.offset[l] = off;
        if ((unsigned long long)G * G * G > (unsigned long long)n) hashedMask |= (1u << l);
        off += n;
    }
    p.hashedMask = hashedMask;

    // workspace: just the f16 table (~24 MB)
    const size_t tabBytes = (size_t)off * 4u;

    if (ws_size >= tabBytes) {
        _Float16* tab = (_Float16*)d_ws;
        const unsigned n4 = off / 2u;  // off is a multiple of 8
        convert_kernel<<<(n4 + BLOCK - 1) / BLOCK, BLOCK, 0, stream>>>(
            (const vfloat4*)emb, (vhalf4*)tab, n4);
        grid_fused_kernel<<<B_POINTS / FBLOCK, FBLOCK, 0, stream>>>(
            inp, tab, out, p);
    } else {
        grid_encode_kernel<<<B_POINTS / BLOCK, BLOCK, 0, stream>>>(inp, emb, out, p);
    }
}

// Round 5
// 612.297 us; speedup vs baseline: 1.5742x; 1.2281x over previous
//
#include <hip/hip_runtime.h>
#include <math.h>

// GridEncoder (instant-NGP hash grid) forward, level-phased two-pass, fp16 table.
// Pre-pass: embeddings f32 -> f16 (x4096 scale keeps values in fp16 normal range);
//           hashed level table = 2MB -> L2-resident per XCD (round-1 proven:
//           FETCH 466MB -> 160MB).
// Pass 1:  level-major dispatch, 2048 blocks/level (= exactly the resident set
//           at 8 blocks/CU x 256 CU -> tight level phasing; round-4 showed
//           phasing is essential: without it FETCH ballooned to 2GB).
//           2 points/thread, straight-line 8-dword gather per point (no parity
//           branch): 16 independent loads in flight -> 2x MLP vs round-1,
//           attacking the latency-bound stall (340us vs 140us request floor).
//           ws written chunk-major [chunk][16][256] half2.
// Pass 2:  per block: one contiguous 16KB ws read -> LDS -> out[B][32] f32.
// BANNED (rounds 2/3): nontemporal table loads (nt evicts L2: FETCH->1.36GB),
//           sc0 inline-asm gathers (returned wrong data). Plain loads only.
// Fixed:   ~130us of total is harness/launch overhead (round-4 2-dispatch
//           pipeline still showed it); transpose is ~30us, near BW floor.

#define NUM_LEVELS 16
#define BLOCK 256
#define B_POINTS (1u << 20)
#define LBLOCKS 2048         // blocks per level (2 pts/thread)
#define P1 2654435761u
#define P2 805459861u
#define HASH_MASK 524287u

#define EMB_SCALE 4096.0f
#define EMB_INV_SCALE (1.0f / 4096.0f)

// pass2 tile: 256 points x 16 levels, half2 (uint) in LDS
#define T2_PTS 256
#define T2_LROW 260   // uint words per level row: 256 + 4 pad

typedef float    vfloat4 __attribute__((ext_vector_type(4)));
typedef unsigned vuint4  __attribute__((ext_vector_type(4)));
typedef _Float16 vhalf2  __attribute__((ext_vector_type(2)));
typedef _Float16 vhalf4  __attribute__((ext_vector_type(4)));

struct Params {
    float    scale[NUM_LEVELS];
    unsigned offset[NUM_LEVELS];
    unsigned G[NUM_LEVELS];
    unsigned hashedMask;
};

struct Prep {
    unsigned u0, u1, u2;
    float f0, f1, f2, m0, m1, m2;
};

__device__ __forceinline__ Prep prep_point(const float* __restrict__ inp,
                                           unsigned b, float s)
{
    const float i0 = inp[3u * b + 0];
    const float i1 = inp[3u * b + 1];
    const float i2 = inp[3u * b + 2];
    const float x0 = __fmul_rn(__fadd_rn(i0, 1.0f), 0.5f);
    const float x1 = __fmul_rn(__fadd_rn(i1, 1.0f), 0.5f);
    const float x2 = __fmul_rn(__fadd_rn(i2, 1.0f), 0.5f);
    const float p0 = __fadd_rn(__fmul_rn(x0, s), 0.5f);
    const float p1 = __fadd_rn(__fmul_rn(x1, s), 0.5f);
    const float p2 = __fadd_rn(__fmul_rn(x2, s), 0.5f);
    const float g0 = floorf(p0), g1 = floorf(p1), g2 = floorf(p2);
    Prep q;
    q.f0 = __fsub_rn(p0, g0); q.f1 = __fsub_rn(p1, g1); q.f2 = __fsub_rn(p2, g2);
    q.u0 = (unsigned)g0; q.u1 = (unsigned)g1; q.u2 = (unsigned)g2;
    q.m0 = __fsub_rn(1.0f, q.f0);
    q.m1 = __fsub_rn(1.0f, q.f1);
    q.m2 = __fsub_rn(1.0f, q.f2);
    return q;
}

// 8 byte-offsets into tab (half2 entries, 4B each) for the hashed gather
__device__ __forceinline__ void hash_offsets(const Prep& q, unsigned base,
                                             unsigned off[8])
{
    const unsigned h1a = q.u1 * P1,        h2a = q.u2 * P2;
    const unsigned h1b = (q.u1 + 1u) * P1, h2b = (q.u2 + 1u) * P2;
#pragma unroll
    for (int k = 0; k < 8; ++k) {
        const unsigned bit0 = (k >> 2) & 1, bit1 = (k >> 1) & 1, bit2 = k & 1;
        const unsigned c0 = q.u0 + bit0;
        const unsigned h  = (bit1 ? h1b : h1a) ^ (bit2 ? h2b : h2a);
        off[k] = 4u * (base + ((c0 ^ h) & HASH_MASK));
    }
}

// ---------------- Pre-pass: f32 -> f16 table conversion (x4096) -----------
__global__ __launch_bounds__(BLOCK) void convert_kernel(
    const vfloat4* __restrict__ emb4, vhalf4* __restrict__ tab4, unsigned n4)
{
    const unsigned i = blockIdx.x * BLOCK + threadIdx.x;
    if (i >= n4) return;
    const vfloat4 v = emb4[i];
    vhalf4 h;
    h.x = (_Float16)(v.x * EMB_SCALE);
    h.y = (_Float16)(v.y * EMB_SCALE);
    h.z = (_Float16)(v.z * EMB_SCALE);
    h.w = (_Float16)(v.w * EMB_SCALE);
    tab4[i] = h;
}

// ---------------- Pass 1: 2 points/thread, straight-line gathers -----------
__global__ __launch_bounds__(BLOCK) void grid_level_kernel(
    const float* __restrict__ inp, const _Float16* __restrict__ tab,
    unsigned* __restrict__ ws, Params p)
{
    const unsigned blk = blockIdx.x;
    const unsigned l   = blk >> 11;                 // level-major dispatch
    const unsigned cp  = blk & 2047u;               // chunk pair
    const unsigned t   = threadIdx.x;
    const unsigned bA  = (cp << 9) | t;             // point A
    const unsigned bB  = bA + 256u;                 // point B (next chunk)

    const float    s      = p.scale[l];
    const unsigned G      = p.G[l];
    const unsigned base   = p.offset[l];
    const bool     hashed = (p.hashedMask >> l) & 1u;   // wave-uniform

    const Prep qA = prep_point(inp, bA, s);
    const Prep qB = prep_point(inp, bB, s);

    float a0A = 0.0f, a1A = 0.0f, a0B = 0.0f, a1B = 0.0f;

    if (hashed) {
        // straight-line: compute all 16 offsets, issue all 16 loads, then FMA.
        unsigned offA[8], offB[8];
        hash_offsets(qA, base, offA);
        hash_offsets(qB, base, offB);
        const char* tc = reinterpret_cast<const char*>(tab);
        unsigned rA[8], rB[8];
#pragma unroll
        for (int k = 0; k < 8; ++k)
            rA[k] = *reinterpret_cast<const unsigned*>(tc + offA[k]);
#pragma unroll
        for (int k = 0; k < 8; ++k)
            rB[k] = *reinterpret_cast<const unsigned*>(tc + offB[k]);
#pragma unroll
        for (int k = 0; k < 8; ++k) {
            const unsigned bit0 = (k >> 2) & 1, bit1 = (k >> 1) & 1, bit2 = k & 1;
            const vhalf2 eA = __builtin_bit_cast(vhalf2, rA[k]);
            const vhalf2 eB = __builtin_bit_cast(vhalf2, rB[k]);
            const float wA = __fmul_rn(
                __fmul_rn(bit0 ? qA.f0 : qA.m0, bit1 ? qA.f1 : qA.m1),
                bit2 ? qA.f2 : qA.m2);
            const float wB = __fmul_rn(
                __fmul_rn(bit0 ? qB.f0 : qB.m0, bit1 ? qB.f1 : qB.m1),
                bit2 ? qB.f2 : qB.m2);
            a0A = fmaf(wA, (float)eA.x, a0A); a1A = fmaf(wA, (float)eA.y, a1A);
            a0B = fmaf(wB, (float)eB.x, a0B); a1B = fmaf(wB, (float)eB.y, a1B);
        }
    } else {
        // dense: dim0 stride 1 -> rows (r, r+1) adjacent: 8B load per corner pair
        const unsigned GG = G * G;
        vhalf4 eA[4], eB[4];
#pragma unroll
        for (int k = 0; k < 4; ++k) {
            const unsigned b1 = (k >> 1) & 1, b2 = k & 1;
            const unsigned rA = qA.u0 + (qA.u1 + b1) * G + (qA.u2 + b2) * GG;
            __builtin_memcpy(&eA[k], tab + 2u * (base + rA), 8);
        }
#pragma unroll
        for (int k = 0; k < 4; ++k) {
            const unsigned b1 = (k >> 1) & 1, b2 = k & 1;
            const unsigned rB = qB.u0 + (qB.u1 + b1) * G + (qB.u2 + b2) * GG;
            __builtin_memcpy(&eB[k], tab + 2u * (base + rB), 8);
        }
#pragma unroll
        for (int k = 0; k < 4; ++k) {
            const unsigned b1 = (k >> 1) & 1, b2 = k & 1;
            const float w12A = __fmul_rn(b1 ? qA.f1 : qA.m1, b2 ? qA.f2 : qA.m2);
            const float waA = __fmul_rn(qA.m0, w12A);
            const float wbA = __fmul_rn(qA.f0, w12A);
            a0A = fmaf(waA, (float)eA[k].x, a0A); a1A = fmaf(waA, (float)eA[k].y, a1A);
            a0A = fmaf(wbA, (float)eA[k].z, a0A); a1A = fmaf(wbA, (float)eA[k].w, a1A);
            const float w12B = __fmul_rn(b1 ? qB.f1 : qB.m1, b2 ? qB.f2 : qB.m2);
            const float waB = __fmul_rn(qB.m0, w12B);
            const float wbB = __fmul_rn(qB.f0, w12B);
            a0B = fmaf(waB, (float)eB[k].x, a0B); a1B = fmaf(waB, (float)eB[k].y, a1B);
            a0B = fmaf(wbB, (float)eB[k].z, a0B); a1B = fmaf(wbB, (float)eB[k].w, a1B);
        }
    }

    // ws layout: [chunk][level][256] half2 -> pass2 reads 16KB contiguous/block
    const unsigned c0 = cp << 1;
    vhalf2 hvA; hvA.x = (_Float16)a0A; hvA.y = (_Float16)a1A;
    vhalf2 hvB; hvB.x = (_Float16)a0B; hvB.y = (_Float16)a1B;
    __builtin_nontemporal_store(
        __builtin_bit_cast(unsigned, hvA),
        ws + (size_t)c0 * (NUM_LEVELS * BLOCK) + l * BLOCK + t);
    __builtin_nontemporal_store(
        __builtin_bit_cast(unsigned, hvB),
        ws + (size_t)(c0 + 1u) * (NUM_LEVELS * BLOCK) + l * BLOCK + t);
}

// ---------------- Pass 2: ws[chunk][16][256] -> out[B][32] ------------------
__global__ __launch_bounds__(BLOCK) void transpose_kernel(
    const unsigned* __restrict__ ws, float* __restrict__ out)
{
    __shared__ unsigned tile[NUM_LEVELS * T2_LROW];   // 16 x 260 x 4B = 16.6 KB
    const unsigned t = threadIdx.x;
    const unsigned c = blockIdx.x;

    // load: one contiguous 16KB segment = 1024 uint4; 4 rounds x 256 threads
    const vuint4* src = reinterpret_cast<const vuint4*>(
        ws + (size_t)c * (NUM_LEVELS * T2_PTS));
#pragma unroll
    for (int r = 0; r < 4; ++r) {
        const unsigned flat = r * BLOCK + t;     // uint4 id; 64 uint4 per level
        const unsigned l = flat >> 6;
        const unsigned i = flat & 63u;
        const vuint4 v = __builtin_nontemporal_load(src + flat);
        *reinterpret_cast<vuint4*>(&tile[l * T2_LROW + 4u * i]) = v;
    }
    __syncthreads();

    // store: 256 pts x 8 float4 = 2048; 8 rounds, contiguous 4KB each
    vfloat4* ov = reinterpret_cast<vfloat4*>(out) + (size_t)c * (T2_PTS * 8u);
#pragma unroll
    for (int r = 0; r < 8; ++r) {
        const unsigned idx = r * BLOCK + t;
        const unsigned pt = idx >> 3;
        const unsigned j  = idx & 7u;            // level pair
        const vhalf2 e0 = __builtin_bit_cast(vhalf2, tile[(2u * j)      * T2_LROW + pt]);
        const vhalf2 e1 = __builtin_bit_cast(vhalf2, tile[(2u * j + 1u) * T2_LROW + pt]);
        vfloat4 v;
        v.x = (float)e0.x * EMB_INV_SCALE;
        v.y = (float)e0.y * EMB_INV_SCALE;
        v.z = (float)e1.x * EMB_INV_SCALE;
        v.w = (float)e1.y * EMB_INV_SCALE;
        __builtin_nontemporal_store(v, ov + idx);
    }
}

// ---------------- Fallback: monolithic f32 (used only if ws too small) -----
__global__ __launch_bounds__(BLOCK) void grid_encode_kernel(
    const float* __restrict__ inp, const float2* __restrict__ emb,
    float* __restrict__ out, Params p)
{
    const unsigned b = blockIdx.x * BLOCK + threadIdx.x;
    const float i0 = inp[3u * b + 0], i1 = inp[3u * b + 1], i2 = inp[3u * b + 2];
    const float x0 = __fmul_rn(__fadd_rn(i0, 1.0f), 0.5f);
    const float x1 = __fmul_rn(__fadd_rn(i1, 1.0f), 0.5f);
    const float x2 = __fmul_rn(__fadd_rn(i2, 1.0f), 0.5f);
    float o[2 * NUM_LEVELS];
#pragma unroll
    for (int l = 0; l < NUM_LEVELS; ++l) {
        const float s = p.scale[l];
        const unsigned G = p.G[l], base = p.offset[l];
        const bool hashed = (p.hashedMask >> l) & 1u;
        const float p0 = __fadd_rn(__fmul_rn(x0, s), 0.5f);
        const float p1 = __fadd_rn(__fmul_rn(x1, s), 0.5f);
        const float p2 = __fadd_rn(__fmul_rn(x2, s), 0.5f);
        const float g0 = floorf(p0), g1 = floorf(p1), g2 = floorf(p2);
        const float f0 = __fsub_rn(p0, g0), f1 = __fsub_rn(p1, g1), f2 = __fsub_rn(p2, g2);
        const unsigned u0 = (unsigned)g0, u1 = (unsigned)g1, u2 = (unsigned)g2;
        const float m0 = __fsub_rn(1.0f, f0), m1 = __fsub_rn(1.0f, f1), m2 = __fsub_rn(1.0f, f2);
        float a0 = 0.0f, a1 = 0.0f;
#pragma unroll
        for (int k = 0; k < 8; ++k) {
            const unsigned bit0 = (k >> 2) & 1, bit1 = (k >> 1) & 1, bit2 = k & 1;
            const unsigned c0 = u0 + bit0, c1 = u1 + bit1, c2 = u2 + bit2;
            unsigned idx;
            if (hashed) idx = (c0 ^ (c1 * P1) ^ (c2 * P2)) & HASH_MASK;
            else        idx = c0 + c1 * G + c2 * G * G;
            const float2 e = emb[(size_t)(base + idx)];
            const float w = __fmul_rn(__fmul_rn(bit0 ? f0 : m0, bit1 ? f1 : m1),
                                      bit2 ? f2 : m2);
            a0 = fmaf(w, e.x, a0); a1 = fmaf(w, e.y, a1);
        }
        o[2 * l] = a0; o[2 * l + 1] = a1;
    }
    float4* ov = reinterpret_cast<float4*>(out + (size_t)b * 32u);
#pragma unroll
    for (int j = 0; j < 8; ++j)
        ov[j] = make_float4(o[4 * j], o[4 * j + 1], o[4 * j + 2], o[4 * j + 3]);
}

extern "C" void kernel_launch(void* const* d_in, const int* in_sizes, int n_in,
                              void* d_out, int out_size, void* d_ws, size_t ws_size,
                              hipStream_t stream) {
    const float*  inp = (const float*)d_in[0];
    const float2* emb = (const float2*)d_in[1];
    float*        out = (float*)d_out;

    // Host-side replication of reference level setup (same libm chain as numpy).
    Params p;
    const double PLS = exp2(log2(2048.0 / 16.0) / 15.0);
    const double S   = log2(PLS);
    unsigned off = 0, hashedMask = 0;
    for (int l = 0; l < NUM_LEVELS; ++l) {
        const double sc_d = exp2((double)l * S) * 16.0 - 1.0;
        const float  sc   = (float)sc_d;
        p.scale[l] = sc;
        const unsigned G = (unsigned)ceilf(sc) + 2u;
        p.G[l] = G;
        const unsigned res = (unsigned)(ceil(16.0 * pow(PLS, (double)l))) + 1u;
        unsigned long long cube = (unsigned long long)res * res * res;
        unsigned long long nll  = cube < 524288ull ? cube : 524288ull;
        unsigned n = (unsigned)((nll + 7ull) / 8ull * 8ull);
        p.offset[l] = off;
        if ((unsigned long long)G * G * G > (unsigned long long)n) hashedMask |= (1u << l);
        off += n;
    }
    p.hashedMask = hashedMask;

    // workspace layout: [f16 table (x4096)] [ws half2, chunk-major 16 x B]
    const size_t tabBytes = ((size_t)off * 4u + 4095u) & ~(size_t)4095u;  // ~24 MB
    const size_t wsBytes  = (size_t)NUM_LEVELS * B_POINTS * 4u;           // 64 MB
    const size_t ws_needed = tabBytes + wsBytes;                          // ~88 MB

    if (ws_size >= ws_needed) {
        _Float16* tab  = (_Float16*)d_ws;
        unsigned* ws_u = (unsigned*)((char*)d_ws + tabBytes);
        const unsigned n4 = off / 2u;  // off is a multiple of 8
        convert_kernel<<<(n4 + BLOCK - 1) / BLOCK, BLOCK, 0, stream>>>(
            (const vfloat4*)emb, (vhalf4*)tab, n4);
        grid_level_kernel<<<NUM_LEVELS * LBLOCKS, BLOCK, 0, stream>>>(
            inp, tab, ws_u, p);
        transpose_kernel<<<B_POINTS / T2_PTS, BLOCK, 0, stream>>>(ws_u, out);
    } else {
        grid_encode_kernel<<<B_POINTS / BLOCK, BLOCK, 0, stream>>>(inp, emb, out, p);
    }
}

// Round 7
// 482.356 us; speedup vs baseline: 1.9983x; 1.2694x over previous
//
#include <hip/hip_runtime.h>
#include <math.h>

// GridEncoder (instant-NGP hash grid) forward, level-phased two-pass, fp16 table.
// Pre-pass: embeddings f32 -> f16 (x4096 scale keeps values in fp16 normal range);
//           hashed level table = 2MB -> L2-resident per XCD (round-1 proven).
// Pass 1:  level-major dispatch, 4096 blocks/level (tight level phasing; round-4
//           showed phasing is essential). PASS-1 IS REQUEST-RATE BOUND:
//           r1 (86M lane-requests, 340us) and r5 (108M, 440us) both sit at
//           0.41 req/cy/CU (~13 req/cy/XCD-L2); MLP and request width do not
//           matter, only request COUNT. This round: dim0 corner pairs satisfy
//           idxB = idxA ^ (u0^(u0+1)); span is 1 or 3 (same aligned 16B group
//           of 4 entries) for 75% of lanes -> one dwordx4 covers both corners;
//           25% of lanes take an exec-masked spill dword. Hashed requests
//           6 -> 5 per point (86M -> 75M total).
// Pass 2:  per block: one contiguous 16KB ws read -> LDS -> out[B][32] f32.
// BANNED (rounds 2/3): nontemporal table loads (nt evicts L2: FETCH->1.36GB),
//           sc0 inline-asm gathers (returned wrong data). Plain loads only.
// Fixed:   ~130us of total is harness overhead (invariant across 2 vs 3
//           dispatches); transpose ~30us is at BW floor.
// (Round 6 was an infra failure - this source is the round-5 proposal, resubmitted.)

#define NUM_LEVELS 16
#define BLOCK 256
#define B_POINTS (1u << 20)
#define LEVEL_BLOCKS (B_POINTS / BLOCK)  // 4096
#define P1 2654435761u
#define P2 805459861u
#define HASH_MASK 524287u

#define EMB_SCALE 4096.0f
#define EMB_INV_SCALE (1.0f / 4096.0f)

// pass2 tile: 256 points x 16 levels, half2 (uint) in LDS
#define T2_PTS 256
#define T2_LROW 260   // uint words per level row: 256 + 4 pad

typedef float    vfloat4 __attribute__((ext_vector_type(4)));
typedef unsigned vuint4  __attribute__((ext_vector_type(4)));
typedef _Float16 vhalf2  __attribute__((ext_vector_type(2)));
typedef _Float16 vhalf4  __attribute__((ext_vector_type(4)));

struct Params {
    float    scale[NUM_LEVELS];
    unsigned offset[NUM_LEVELS];
    unsigned G[NUM_LEVELS];
    unsigned hashedMask;
};

// select entry s (0..3) from an aligned 4-entry group held in 4 VGPRs
__device__ __forceinline__ unsigned sel4(vuint4 q, unsigned s) {
    const unsigned lo = (s & 1u) ? q.y : q.x;
    const unsigned hi = (s & 1u) ? q.w : q.z;
    return (s & 2u) ? hi : lo;
}

// ---------------- Pre-pass: f32 -> f16 table conversion (x4096) -----------
__global__ __launch_bounds__(BLOCK) void convert_kernel(
    const vfloat4* __restrict__ emb4, vhalf4* __restrict__ tab4, unsigned n4)
{
    const unsigned i = blockIdx.x * BLOCK + threadIdx.x;
    if (i >= n4) return;
    const vfloat4 v = emb4[i];
    vhalf4 h;
    h.x = (_Float16)(v.x * EMB_SCALE);
    h.y = (_Float16)(v.y * EMB_SCALE);
    h.z = (_Float16)(v.z * EMB_SCALE);
    h.w = (_Float16)(v.w * EMB_SCALE);
    tab4[i] = h;
}

// ---------------- Pass 1 ----------------
__global__ __launch_bounds__(BLOCK) void grid_level_kernel(
    const float* __restrict__ inp, const unsigned* __restrict__ tabu,
    unsigned* __restrict__ ws, Params p)
{
    const unsigned blk   = blockIdx.x;
    const unsigned l     = blk >> 12;                    // level-major dispatch
    const unsigned chunk = blk & 4095u;
    const unsigned t     = threadIdx.x;
    const unsigned b     = (chunk << 8) | t;

    const float    s      = p.scale[l];
    const unsigned G      = p.G[l];
    const unsigned base   = p.offset[l];                 // multiple of 8 entries
    const bool     hashed = (p.hashedMask >> l) & 1u;    // wave-uniform

    const float i0 = inp[3u * b + 0];
    const float i1 = inp[3u * b + 1];
    const float i2 = inp[3u * b + 2];
    const float x0 = __fmul_rn(__fadd_rn(i0, 1.0f), 0.5f);
    const float x1 = __fmul_rn(__fadd_rn(i1, 1.0f), 0.5f);
    const float x2 = __fmul_rn(__fadd_rn(i2, 1.0f), 0.5f);

    const float p0 = __fadd_rn(__fmul_rn(x0, s), 0.5f);
    const float p1 = __fadd_rn(__fmul_rn(x1, s), 0.5f);
    const float p2 = __fadd_rn(__fmul_rn(x2, s), 0.5f);
    const float g0 = floorf(p0), g1 = floorf(p1), g2 = floorf(p2);
    const float f0 = __fsub_rn(p0, g0);
    const float f1 = __fsub_rn(p1, g1);
    const float f2 = __fsub_rn(p2, g2);
    const unsigned u0 = (unsigned)g0, u1 = (unsigned)g1, u2 = (unsigned)g2;
    const float m0 = __fsub_rn(1.0f, f0);
    const float m1 = __fsub_rn(1.0f, f1);
    const float m2 = __fsub_rn(1.0f, f2);

    float a0 = 0.0f, a1 = 0.0f;

    if (hashed) {
        const unsigned h1a = u1 * P1,        h2a = u2 * P2;
        const unsigned h1b = (u1 + 1u) * P1, h2b = (u2 + 1u) * P2;
        const unsigned x01 = u0 ^ (u0 + 1u);   // dim0-pair XOR span (per-lane const)
        const bool spill = x01 > 3u;           // 25% of lanes: pair leaves 16B group

        unsigned idxA[4], idxB[4], eAu[4], eBu[4];
#pragma unroll
        for (int k = 0; k < 4; ++k) {
            const unsigned b1 = (k >> 1) & 1, b2 = k & 1;
            const unsigned h  = (b1 ? h1b : h1a) ^ (b2 ? h2b : h2a);
            idxA[k] = (u0 ^ h) & HASH_MASK;
            idxB[k] = idxA[k] ^ x01;           // == ((u0+1)^h) & HASH_MASK
        }
        // 4 aligned 16B group loads (each covers corner A; covers B iff !spill)
        vuint4 q[4];
#pragma unroll
        for (int k = 0; k < 4; ++k)
            q[k] = *reinterpret_cast<const vuint4*>(tabu + base + (idxA[k] & ~3u));
#pragma unroll
        for (int k = 0; k < 4; ++k)
            eAu[k] = sel4(q[k], idxA[k] & 3u);
        if (spill) {
            // exec-masked: only ~25% of lanes issue these 4 extra dword requests
#pragma unroll
            for (int k = 0; k < 4; ++k)
                eBu[k] = tabu[base + idxB[k]];
        } else {
#pragma unroll
            for (int k = 0; k < 4; ++k)
                eBu[k] = sel4(q[k], idxB[k] & 3u);
        }
#pragma unroll
        for (int k = 0; k < 4; ++k) {
            const unsigned b1 = (k >> 1) & 1, b2 = k & 1;
            const vhalf2 eA = __builtin_bit_cast(vhalf2, eAu[k]);
            const vhalf2 eB = __builtin_bit_cast(vhalf2, eBu[k]);
            const float w12 = __fmul_rn(b1 ? f1 : m1, b2 ? f2 : m2);
            const float wa = __fmul_rn(m0, w12);   // corner c0 = u0
            const float wb = __fmul_rn(f0, w12);   // corner c0 = u0+1
            a0 = fmaf(wa, (float)eA.x, a0); a1 = fmaf(wa, (float)eA.y, a1);
            a0 = fmaf(wb, (float)eB.x, a0); a1 = fmaf(wb, (float)eB.y, a1);
        }
    } else {
        // dense: dim0 stride 1 -> rows (r, r+1) adjacent: 8B load per corner pair
        const unsigned GG = G * G;
        const _Float16* tab = reinterpret_cast<const _Float16*>(tabu);
#pragma unroll
        for (int k = 0; k < 4; ++k) {
            const unsigned b1 = (k >> 1) & 1, b2 = k & 1;
            const unsigned r = u0 + (u1 + b1) * G + (u2 + b2) * GG;
            vhalf4 e4;
            __builtin_memcpy(&e4, tab + 2u * (base + r), 8);
            const float w12 = __fmul_rn(b1 ? f1 : m1, b2 ? f2 : m2);
            const float wa = __fmul_rn(m0, w12);
            const float wb = __fmul_rn(f0, w12);
            a0 = fmaf(wa, (float)e4.x, a0); a1 = fmaf(wa, (float)e4.y, a1);
            a0 = fmaf(wb, (float)e4.z, a0); a1 = fmaf(wb, (float)e4.w, a1);
        }
    }

    // ws layout: [chunk][level][256] half2 -> pass2 reads 16KB contiguous/block
    vhalf2 hv;
    hv.x = (_Float16)a0;
    hv.y = (_Float16)a1;
    __builtin_nontemporal_store(
        __builtin_bit_cast(unsigned, hv),
        ws + (size_t)chunk * (NUM_LEVELS * BLOCK) + l * BLOCK + t);
}

// ---------------- Pass 2: ws[chunk][16][256] -> out[B][32] ------------------
__global__ __launch_bounds__(BLOCK) void transpose_kernel(
    const unsigned* __restrict__ ws, float* __restrict__ out)
{
    __shared__ unsigned tile[NUM_LEVELS * T2_LROW];   // 16 x 260 x 4B = 16.6 KB
    const unsigned t = threadIdx.x;
    const unsigned c = blockIdx.x;

    // load: one contiguous 16KB segment = 1024 uint4; 4 rounds x 256 threads
    const vuint4* src = reinterpret_cast<const vuint4*>(
        ws + (size_t)c * (NUM_LEVELS * T2_PTS));
#pragma unroll
    for (int r = 0; r < 4; ++r) {
        const unsigned flat = r * BLOCK + t;     // uint4 id; 64 uint4 per level
        const unsigned l = flat >> 6;
        const unsigned i = flat & 63u;
        const vuint4 v = __builtin_nontemporal_load(src + flat);
        *reinterpret_cast<vuint4*>(&tile[l * T2_LROW + 4u * i]) = v;
    }
    __syncthreads();

    // store: 256 pts x 8 float4 = 2048; 8 rounds, contiguous 4KB each
    vfloat4* ov = reinterpret_cast<vfloat4*>(out) + (size_t)c * (T2_PTS * 8u);
#pragma unroll
    for (int r = 0; r < 8; ++r) {
        const unsigned idx = r * BLOCK + t;
        const unsigned pt = idx >> 3;
        const unsigned j  = idx & 7u;            // level pair
        const vhalf2 e0 = __builtin_bit_cast(vhalf2, tile[(2u * j)      * T2_LROW + pt]);
        const vhalf2 e1 = __builtin_bit_cast(vhalf2, tile[(2u * j + 1u) * T2_LROW + pt]);
        vfloat4 v;
        v.x = (float)e0.x * EMB_INV_SCALE;
        v.y = (float)e0.y * EMB_INV_SCALE;
        v.z = (float)e1.x * EMB_INV_SCALE;
        v.w = (float)e1.y * EMB_INV_SCALE;
        __builtin_nontemporal_store(v, ov + idx);
    }
}

// ---------------- Fallback: monolithic f32 (used only if ws too small) -----
__global__ __launch_bounds__(BLOCK) void grid_encode_kernel(
    const float* __restrict__ inp, const float2* __restrict__ emb,
    float* __restrict__ out, Params p)
{
    const unsigned b = blockIdx.x * BLOCK + threadIdx.x;
    const float i0 = inp[3u * b + 0], i1 = inp[3u * b + 1], i2 = inp[3u * b + 2];
    const float x0 = __fmul_rn(__fadd_rn(i0, 1.0f), 0.5f);
    const float x1 = __fmul_rn(__fadd_rn(i1, 1.0f), 0.5f);
    const float x2 = __fmul_rn(__fadd_rn(i2, 1.0f), 0.5f);
    float o[2 * NUM_LEVELS];
#pragma unroll
    for (int l = 0; l < NUM_LEVELS; ++l) {
        const float s = p.scale[l];
        const unsigned G = p.G[l], base = p.offset[l];
        const bool hashed = (p.hashedMask >> l) & 1u;
        const float p0 = __fadd_rn(__fmul_rn(x0, s), 0.5f);
        const float p1 = __fadd_rn(__fmul_rn(x1, s), 0.5f);
        const float p2 = __fadd_rn(__fmul_rn(x2, s), 0.5f);
        const float g0 = floorf(p0), g1 = floorf(p1), g2 = floorf(p2);
        const float f0 = __fsub_rn(p0, g0), f1 = __fsub_rn(p1, g1), f2 = __fsub_rn(p2, g2);
        const unsigned u0 = (unsigned)g0, u1 = (unsigned)g1, u2 = (unsigned)g2;
        const float m0 = __fsub_rn(1.0f, f0), m1 = __fsub_rn(1.0f, f1), m2 = __fsub_rn(1.0f, f2);
        float a0 = 0.0f, a1 = 0.0f;
#pragma unroll
        for (int k = 0; k < 8; ++k) {
            const unsigned bit0 = (k >> 2) & 1, bit1 = (k >> 1) & 1, bit2 = k & 1;
            const unsigned c0 = u0 + bit0, c1 = u1 + bit1, c2 = u2 + bit2;
            unsigned idx;
            if (hashed) idx = (c0 ^ (c1 * P1) ^ (c2 * P2)) & HASH_MASK;
            else        idx = c0 + c1 * G + c2 * G * G;
            const float2 e = emb[(size_t)(base + idx)];
            const float w = __fmul_rn(__fmul_rn(bit0 ? f0 : m0, bit1 ? f1 : m1),
                                      bit2 ? f2 : m2);
            a0 = fmaf(w, e.x, a0); a1 = fmaf(w, e.y, a1);
        }
        o[2 * l] = a0; o[2 * l + 1] = a1;
    }
    float4* ov = reinterpret_cast<float4*>(out + (size_t)b * 32u);
#pragma unroll
    for (int j = 0; j < 8; ++j)
        ov[j] = make_float4(o[4 * j], o[4 * j + 1], o[4 * j + 2], o[4 * j + 3]);
}

extern "C" void kernel_launch(void* const* d_in, const int* in_sizes, int n_in,
                              void* d_out, int out_size, void* d_ws, size_t ws_size,
                              hipStream_t stream) {
    const float*  inp = (const float*)d_in[0];
    const float2* emb = (const float2*)d_in[1];
    float*        out = (float*)d_out;

    // Host-side replication of reference level setup (same libm chain as numpy).
    Params p;
    const double PLS = exp2(log2(2048.0 / 16.0) / 15.0);
    const double S   = log2(PLS);
    unsigned off = 0, hashedMask = 0;
    for (int l = 0; l < NUM_LEVELS; ++l) {
        const double sc_d = exp2((double)l * S) * 16.0 - 1.0;
        const float  sc   = (float)sc_d;
        p.scale[l] = sc;
        const unsigned G = (unsigned)ceilf(sc) + 2u;
        p.G[l] = G;
        const unsigned res = (unsigned)(ceil(16.0 * pow(PLS, (double)l))) + 1u;
        unsigned long long cube = (unsigned long long)res * res * res;
        unsigned long long nll  = cube < 524288ull ? cube : 524288ull;
        unsigned n = (unsigned)((nll + 7ull) / 8ull * 8ull);
        p.offset[l] = off;
        if ((unsigned long long)G * G * G > (unsigned long long)n) hashedMask |= (1u << l);
        off += n;
    }
    p.hashedMask = hashedMask;

    // workspace layout: [f16 table (x4096)] [ws half2, chunk-major 16 x B]
    const size_t tabBytes = ((size_t)off * 4u + 4095u) & ~(size_t)4095u;  // ~24 MB
    const size_t wsBytes  = (size_t)NUM_LEVELS * B_POINTS * 4u;           // 64 MB
    const size_t ws_needed = tabBytes + wsBytes;                          // ~88 MB

    if (ws_size >= ws_needed) {
        _Float16* tab  = (_Float16*)d_ws;
        unsigned* ws_u = (unsigned*)((char*)d_ws + tabBytes);
        const unsigned n4 = off / 2u;  // off is a multiple of 8
        convert_kernel<<<(n4 + BLOCK - 1) / BLOCK, BLOCK, 0, stream>>>(
            (const vfloat4*)emb, (vhalf4*)tab, n4);
        grid_level_kernel<<<NUM_LEVELS * LEVEL_BLOCKS, BLOCK, 0, stream>>>(
            inp, (const unsigned*)tab, ws_u, p);
        transpose_kernel<<<B_POINTS / T2_PTS, BLOCK, 0, stream>>>(ws_u, out);
    } else {
        grid_encode_kernel<<<B_POINTS / BLOCK, BLOCK, 0, stream>>>(inp, emb, out, p);
    }
}

// Round 8
// 478.808 us; speedup vs baseline: 2.0131x; 1.0074x over previous
//
#include <hip/hip_runtime.h>
#include <math.h>

// GridEncoder (instant-NGP hash grid) forward, level-phased, fp16 table.
// MODEL (r1/r5/r7 confirmed): pass-1 time = divergent-VMEM-lane-requests x
//   (1 / 0.41 req/cy/CU); 86M->340us, 108M->440us, 75M->312us. Only request
//   COUNT matters (not MLP, not width). Optimization = remove requests.
// Pre-pass: embeddings f32 -> f16 (x4096 scale; fp16-normal range);
//           hashed level table = 2MB -> L2-resident per XCD.
// DenseLow: levels 0-1 (tables 19.7KB / 55.3KB) in a separate kernel that
//           stages the whole level table into LDS (static 55KB) and gathers
//           via ds_read -> zero VMEM gather requests for these levels.
//           2048 pts/block amortizes staging 8x.
// Pass 1:  levels 2-15, level-major dispatch 4096 blocks/level (phasing is
//           essential - r4). Hashed: 4 aligned dwordx4 group loads cover both
//           dim0 corners for 75% of lanes (idxB = idxA ^ (u0^(u0+1)), span<=3)
//           + exec-masked spill dword for 25%. 67 req/pt total (was 75).
// Pass 2:  per block: one contiguous 16KB ws read -> LDS -> out[B][32] f32.
// BANNED (r2/r3): nontemporal table loads (nt evicts L2: FETCH->1.36GB),
//           sc0 inline-asm gathers (wrong data). Plain loads only.
// Fixed:   ~130us of total is harness overhead, invariant in dispatch count.

#define NUM_LEVELS 16
#define BLOCK 256
#define B_POINTS (1u << 20)
#define LEVEL_BLOCKS (B_POINTS / BLOCK)  // 4096
#define LVL_MAIN_START 2                 // main kernel handles levels 2..15
#define P1 2654435761u
#define P2 805459861u
#define HASH_MASK 524287u

#define EMB_SCALE 4096.0f
#define EMB_INV_SCALE (1.0f / 4096.0f)

// dense-low kernel: levels 0-1, table staged in LDS
#define DL_THREADS 1024
#define DL_PTS 2048                      // 2 pts/thread
#define DL_BLOCKS_PER_LVL (B_POINTS / DL_PTS)  // 512
#define DL_MAX_ENTRIES 13824             // level-1 table entries (55296 B)

// pass2 tile: 256 points x 16 levels, half2 (uint) in LDS
#define T2_PTS 256
#define T2_LROW 260   // uint words per level row: 256 + 4 pad

typedef float    vfloat4 __attribute__((ext_vector_type(4)));
typedef unsigned vuint4  __attribute__((ext_vector_type(4)));
typedef _Float16 vhalf2  __attribute__((ext_vector_type(2)));
typedef _Float16 vhalf4  __attribute__((ext_vector_type(4)));

struct Params {
    float    scale[NUM_LEVELS];
    unsigned offset[NUM_LEVELS];
    unsigned G[NUM_LEVELS];
    unsigned hashedMask;
};

// select entry s (0..3) from an aligned 4-entry group held in 4 VGPRs
__device__ __forceinline__ unsigned sel4(vuint4 q, unsigned s) {
    const unsigned lo = (s & 1u) ? q.y : q.x;
    const unsigned hi = (s & 1u) ? q.w : q.z;
    return (s & 2u) ? hi : lo;
}

struct Prep {
    unsigned u0, u1, u2;
    float f0, f1, f2, m0, m1, m2;
};

__device__ __forceinline__ Prep prep_point(const float* __restrict__ inp,
                                           unsigned b, float s)
{
    const float i0 = inp[3u * b + 0];
    const float i1 = inp[3u * b + 1];
    const float i2 = inp[3u * b + 2];
    const float x0 = __fmul_rn(__fadd_rn(i0, 1.0f), 0.5f);
    const float x1 = __fmul_rn(__fadd_rn(i1, 1.0f), 0.5f);
    const float x2 = __fmul_rn(__fadd_rn(i2, 1.0f), 0.5f);
    const float p0 = __fadd_rn(__fmul_rn(x0, s), 0.5f);
    const float p1 = __fadd_rn(__fmul_rn(x1, s), 0.5f);
    const float p2 = __fadd_rn(__fmul_rn(x2, s), 0.5f);
    const float g0 = floorf(p0), g1 = floorf(p1), g2 = floorf(p2);
    Prep q;
    q.f0 = __fsub_rn(p0, g0); q.f1 = __fsub_rn(p1, g1); q.f2 = __fsub_rn(p2, g2);
    q.u0 = (unsigned)g0; q.u1 = (unsigned)g1; q.u2 = (unsigned)g2;
    q.m0 = __fsub_rn(1.0f, q.f0);
    q.m1 = __fsub_rn(1.0f, q.f1);
    q.m2 = __fsub_rn(1.0f, q.f2);
    return q;
}

// ---------------- Pre-pass: f32 -> f16 table conversion (x4096) -----------
__global__ __launch_bounds__(BLOCK) void convert_kernel(
    const vfloat4* __restrict__ emb4, vhalf4* __restrict__ tab4, unsigned n4)
{
    const unsigned i = blockIdx.x * BLOCK + threadIdx.x;
    if (i >= n4) return;
    const vfloat4 v = emb4[i];
    vhalf4 h;
    h.x = (_Float16)(v.x * EMB_SCALE);
    h.y = (_Float16)(v.y * EMB_SCALE);
    h.z = (_Float16)(v.z * EMB_SCALE);
    h.w = (_Float16)(v.w * EMB_SCALE);
    tab4[i] = h;
}

// ---------------- Dense-low: levels 0-1, LDS-staged table ------------------
__global__ __launch_bounds__(DL_THREADS) void dense_low_kernel(
    const float* __restrict__ inp, const unsigned* __restrict__ tabu,
    unsigned* __restrict__ ws, Params p)
{
    __shared__ unsigned sm[DL_MAX_ENTRIES];   // 55296 B (level-1 size)

    const unsigned blk    = blockIdx.x;
    const unsigned level  = blk >> 9;                  // 0 or 1
    const unsigned chunk0 = (blk & 511u) * 8u;         // 8 chunks of 256 pts
    const unsigned t      = threadIdx.x;

    const float    s    = p.scale[level];
    const unsigned G    = p.G[level];
    const unsigned GG   = G * G;
    const unsigned base = p.offset[level];
    const unsigned n    = p.offset[level + 1] - base;  // table entries (mult of 8)

    // stage the whole level table: coalesced dwordx4
    const unsigned n4 = n >> 2;
    for (unsigned i = t; i < n4; i += DL_THREADS) {
        const vuint4 v = *reinterpret_cast<const vuint4*>(tabu + base + 4u * i);
        *reinterpret_cast<vuint4*>(&sm[4u * i]) = v;
    }
    __syncthreads();

#pragma unroll
    for (int h = 0; h < 2; ++h) {
        const unsigned pt = chunk0 * 256u + t + (unsigned)h * DL_THREADS;
        const Prep q = prep_point(inp, pt, s);

        float a0 = 0.0f, a1 = 0.0f;
#pragma unroll
        for (int k = 0; k < 4; ++k) {
            const unsigned b1 = (k >> 1) & 1, b2 = k & 1;
            const unsigned r = q.u0 + (q.u1 + b1) * G + (q.u2 + b2) * GG;
            const vhalf2 e0 = __builtin_bit_cast(vhalf2, sm[r]);
            const vhalf2 e1 = __builtin_bit_cast(vhalf2, sm[r + 1u]);
            const float w12 = __fmul_rn(b1 ? q.f1 : q.m1, b2 ? q.f2 : q.m2);
            const float wa = __fmul_rn(q.m0, w12);
            const float wb = __fmul_rn(q.f0, w12);
            a0 = fmaf(wa, (float)e0.x, a0); a1 = fmaf(wa, (float)e0.y, a1);
            a0 = fmaf(wb, (float)e1.x, a0); a1 = fmaf(wb, (float)e1.y, a1);
        }

        vhalf2 hv;
        hv.x = (_Float16)a0;
        hv.y = (_Float16)a1;
        __builtin_nontemporal_store(
            __builtin_bit_cast(unsigned, hv),
            ws + (size_t)(pt >> 8) * (NUM_LEVELS * BLOCK) + level * BLOCK + (pt & 255u));
    }
}

// ---------------- Pass 1: levels 2..15 ----------------
__global__ __launch_bounds__(BLOCK) void grid_level_kernel(
    const float* __restrict__ inp, const unsigned* __restrict__ tabu,
    unsigned* __restrict__ ws, Params p)
{
    const unsigned blk   = blockIdx.x;
    const unsigned l     = LVL_MAIN_START + (blk >> 12);   // level-major dispatch
    const unsigned chunk = blk & 4095u;
    const unsigned t     = threadIdx.x;
    const unsigned b     = (chunk << 8) | t;

    const float    s      = p.scale[l];
    const unsigned G      = p.G[l];
    const unsigned base   = p.offset[l];                 // multiple of 8 entries
    const bool     hashed = (p.hashedMask >> l) & 1u;    // wave-uniform

    const Prep q = prep_point(inp, b, s);
    const unsigned u0 = q.u0, u1 = q.u1, u2 = q.u2;
    const float f0 = q.f0, f1 = q.f1, f2 = q.f2;
    const float m0 = q.m0, m1 = q.m1, m2 = q.m2;

    float a0 = 0.0f, a1 = 0.0f;

    if (hashed) {
        const unsigned h1a = u1 * P1,        h2a = u2 * P2;
        const unsigned h1b = (u1 + 1u) * P1, h2b = (u2 + 1u) * P2;
        const unsigned x01 = u0 ^ (u0 + 1u);   // dim0-pair XOR span (per-lane const)
        const bool spill = x01 > 3u;           // 25% of lanes: pair leaves 16B group

        unsigned idxA[4], idxB[4], eAu[4], eBu[4];
#pragma unroll
        for (int k = 0; k < 4; ++k) {
            const unsigned b1 = (k >> 1) & 1, b2 = k & 1;
            const unsigned h  = (b1 ? h1b : h1a) ^ (b2 ? h2b : h2a);
            idxA[k] = (u0 ^ h) & HASH_MASK;
            idxB[k] = idxA[k] ^ x01;           // == ((u0+1)^h) & HASH_MASK
        }
        // 4 aligned 16B group loads (each covers corner A; covers B iff !spill)
        vuint4 qv[4];
#pragma unroll
        for (int k = 0; k < 4; ++k)
            qv[k] = *reinterpret_cast<const vuint4*>(tabu + base + (idxA[k] & ~3u));
#pragma unroll
        for (int k = 0; k < 4; ++k)
            eAu[k] = sel4(qv[k], idxA[k] & 3u);
        if (spill) {
            // exec-masked: only ~25% of lanes issue these 4 extra dword requests
#pragma unroll
            for (int k = 0; k < 4; ++k)
                eBu[k] = tabu[base + idxB[k]];
        } else {
#pragma unroll
            for (int k = 0; k < 4; ++k)
                eBu[k] = sel4(qv[k], idxB[k] & 3u);
        }
#pragma unroll
        for (int k = 0; k < 4; ++k) {
            const unsigned b1 = (k >> 1) & 1, b2 = k & 1;
            const vhalf2 eA = __builtin_bit_cast(vhalf2, eAu[k]);
            const vhalf2 eB = __builtin_bit_cast(vhalf2, eBu[k]);
            const float w12 = __fmul_rn(b1 ? f1 : m1, b2 ? f2 : m2);
            const float wa = __fmul_rn(m0, w12);   // corner c0 = u0
            const float wb = __fmul_rn(f0, w12);   // corner c0 = u0+1
            a0 = fmaf(wa, (float)eA.x, a0); a1 = fmaf(wa, (float)eA.y, a1);
            a0 = fmaf(wb, (float)eB.x, a0); a1 = fmaf(wb, (float)eB.y, a1);
        }
    } else {
        // dense: dim0 stride 1 -> rows (r, r+1) adjacent: 8B load per corner pair
        const unsigned GG = G * G;
        const _Float16* tab = reinterpret_cast<const _Float16*>(tabu);
#pragma unroll
        for (int k = 0; k < 4; ++k) {
            const unsigned b1 = (k >> 1) & 1, b2 = k & 1;
            const unsigned r = u0 + (u1 + b1) * G + (u2 + b2) * GG;
            vhalf4 e4;
            __builtin_memcpy(&e4, tab + 2u * (base + r), 8);
            const float w12 = __fmul_rn(b1 ? f1 : m1, b2 ? f2 : m2);
            const float wa = __fmul_rn(m0, w12);
            const float wb = __fmul_rn(f0, w12);
            a0 = fmaf(wa, (float)e4.x, a0); a1 = fmaf(wa, (float)e4.y, a1);
            a0 = fmaf(wb, (float)e4.z, a0); a1 = fmaf(wb, (float)e4.w, a1);
        }
    }

    // ws layout: [chunk][level][256] half2 -> pass2 reads 16KB contiguous/block
    vhalf2 hv;
    hv.x = (_Float16)a0;
    hv.y = (_Float16)a1;
    __builtin_nontemporal_store(
        __builtin_bit_cast(unsigned, hv),
        ws + (size_t)chunk * (NUM_LEVELS * BLOCK) + l * BLOCK + t);
}

// ---------------- Pass 2: ws[chunk][16][256] -> out[B][32] ------------------
__global__ __launch_bounds__(BLOCK) void transpose_kernel(
    const unsigned* __restrict__ ws, float* __restrict__ out)
{
    __shared__ unsigned tile[NUM_LEVELS * T2_LROW];   // 16 x 260 x 4B = 16.6 KB
    const unsigned t = threadIdx.x;
    const unsigned c = blockIdx.x;

    // load: one contiguous 16KB segment = 1024 uint4; 4 rounds x 256 threads
    const vuint4* src = reinterpret_cast<const vuint4*>(
        ws + (size_t)c * (NUM_LEVELS * T2_PTS));
#pragma unroll
    for (int r = 0; r < 4; ++r) {
        const unsigned flat = r * BLOCK + t;     // uint4 id; 64 uint4 per level
        const unsigned l = flat >> 6;
        const unsigned i = flat & 63u;
        const vuint4 v = __builtin_nontemporal_load(src + flat);
        *reinterpret_cast<vuint4*>(&tile[l * T2_LROW + 4u * i]) = v;
    }
    __syncthreads();

    // store: 256 pts x 8 float4 = 2048; 8 rounds, contiguous 4KB each
    vfloat4* ov = reinterpret_cast<vfloat4*>(out) + (size_t)c * (T2_PTS * 8u);
#pragma unroll
    for (int r = 0; r < 8; ++r) {
        const unsigned idx = r * BLOCK + t;
        const unsigned pt = idx >> 3;
        const unsigned j  = idx & 7u;            // level pair
        const vhalf2 e0 = __builtin_bit_cast(vhalf2, tile[(2u * j)      * T2_LROW + pt]);
        const vhalf2 e1 = __builtin_bit_cast(vhalf2, tile[(2u * j + 1u) * T2_LROW + pt]);
        vfloat4 v;
        v.x = (float)e0.x * EMB_INV_SCALE;
        v.y = (float)e0.y * EMB_INV_SCALE;
        v.z = (float)e1.x * EMB_INV_SCALE;
        v.w = (float)e1.y * EMB_INV_SCALE;
        __builtin_nontemporal_store(v, ov + idx);
    }
}

// ---------------- Fallback: monolithic f32 (used only if ws too small) -----
__global__ __launch_bounds__(BLOCK) void grid_encode_kernel(
    const float* __restrict__ inp, const float2* __restrict__ emb,
    float* __restrict__ out, Params p)
{
    const unsigned b = blockIdx.x * BLOCK + threadIdx.x;
    const float i0 = inp[3u * b + 0], i1 = inp[3u * b + 1], i2 = inp[3u * b + 2];
    const float x0 = __fmul_rn(__fadd_rn(i0, 1.0f), 0.5f);
    const float x1 = __fmul_rn(__fadd_rn(i1, 1.0f), 0.5f);
    const float x2 = __fmul_rn(__fadd_rn(i2, 1.0f), 0.5f);
    float o[2 * NUM_LEVELS];
#pragma unroll
    for (int l = 0; l < NUM_LEVELS; ++l) {
        const float s = p.scale[l];
        const unsigned G = p.G[l], base = p.offset[l];
        const bool hashed = (p.hashedMask >> l) & 1u;
        const float p0 = __fadd_rn(__fmul_rn(x0, s), 0.5f);
        const float p1 = __fadd_rn(__fmul_rn(x1, s), 0.5f);
        const float p2 = __fadd_rn(__fmul_rn(x2, s), 0.5f);
        const float g0 = floorf(p0), g1 = floorf(p1), g2 = floorf(p2);
        const float f0 = __fsub_rn(p0, g0), f1 = __fsub_rn(p1, g1), f2 = __fsub_rn(p2, g2);
        const unsigned u0 = (unsigned)g0, u1 = (unsigned)g1, u2 = (unsigned)g2;
        const float m0 = __fsub_rn(1.0f, f0), m1 = __fsub_rn(1.0f, f1), m2 = __fsub_rn(1.0f, f2);
        float a0 = 0.0f, a1 = 0.0f;
#pragma unroll
        for (int k = 0; k < 8; ++k) {
            const unsigned bit0 = (k >> 2) & 1, bit1 = (k >> 1) & 1, bit2 = k & 1;
            const unsigned c0 = u0 + bit0, c1 = u1 + bit1, c2 = u2 + bit2;
            unsigned idx;
            if (hashed) idx = (c0 ^ (c1 * P1) ^ (c2 * P2)) & HASH_MASK;
            else        idx = c0 + c1 * G + c2 * G * G;
            const float2 e = emb[(size_t)(base + idx)];
            const float w = __fmul_rn(__fmul_rn(bit0 ? f0 : m0, bit1 ? f1 : m1),
                                      bit2 ? f2 : m2);
            a0 = fmaf(w, e.x, a0); a1 = fmaf(w, e.y, a1);
        }
        o[2 * l] = a0; o[2 * l + 1] = a1;
    }
    float4* ov = reinterpret_cast<float4*>(out + (size_t)b * 32u);
#pragma unroll
    for (int j = 0; j < 8; ++j)
        ov[j] = make_float4(o[4 * j], o[4 * j + 1], o[4 * j + 2], o[4 * j + 3]);
}

extern "C" void kernel_launch(void* const* d_in, const int* in_sizes, int n_in,
                              void* d_out, int out_size, void* d_ws, size_t ws_size,
                              hipStream_t stream) {
    const float*  inp = (const float*)d_in[0];
    const float2* emb = (const float2*)d_in[1];
    float*        out = (float*)d_out;

    // Host-side replication of reference level setup (same libm chain as numpy).
    Params p;
    const double PLS = exp2(log2(2048.0 / 16.0) / 15.0);
    const double S   = log2(PLS);
    unsigned off = 0, hashedMask = 0;
    for (int l = 0; l < NUM_LEVELS; ++l) {
        const double sc_d = exp2((double)l * S) * 16.0 - 1.0;
        const float  sc   = (float)sc_d;
        p.scale[l] = sc;
        const unsigned G = (unsigned)ceilf(sc) + 2u;
        p.G[l] = G;
        const unsigned res = (unsigned)(ceil(16.0 * pow(PLS, (double)l))) + 1u;
        unsigned long long cube = (unsigned long long)res * res * res;
        unsigned long long nll  = cube < 524288ull ? cube : 524288ull;
        unsigned n = (unsigned)((nll + 7ull) / 8ull * 8ull);
        p.offset[l] = off;
        if ((unsigned long long)G * G * G > (unsigned long long)n) hashedMask |= (1u << l);
        off += n;
    }
    p.hashedMask = hashedMask;

    // workspace layout: [f16 table (x4096)] [ws half2, chunk-major 16 x B]
    const size_t tabBytes = ((size_t)off * 4u + 4095u) & ~(size_t)4095u;  // ~24 MB
    const size_t wsBytes  = (size_t)NUM_LEVELS * B_POINTS * 4u;           // 64 MB
    const size_t ws_needed = tabBytes + wsBytes;                          // ~88 MB

    if (ws_size >= ws_needed) {
        _Float16* tab  = (_Float16*)d_ws;
        unsigned* ws_u = (unsigned*)((char*)d_ws + tabBytes);
        const unsigned n4 = off / 2u;  // off is a multiple of 8
        convert_kernel<<<(n4 + BLOCK - 1) / BLOCK, BLOCK, 0, stream>>>(
            (const vfloat4*)emb, (vhalf4*)tab, n4);
        dense_low_kernel<<<2 * DL_BLOCKS_PER_LVL, DL_THREADS, 0, stream>>>(
            inp, (const unsigned*)tab, ws_u, p);
        grid_level_kernel<<<(NUM_LEVELS - LVL_MAIN_START) * LEVEL_BLOCKS, BLOCK,
                            0, stream>>>(inp, (const unsigned*)tab, ws_u, p);
        transpose_kernel<<<B_POINTS / T2_PTS, BLOCK, 0, stream>>>(ws_u, out);
    } else {
        grid_encode_kernel<<<B_POINTS / BLOCK, BLOCK, 0, stream>>>(inp, emb, out, p);
    }
}